// Round 19
// baseline (453.877 us; speedup 1.0000x reference)
//
#include <hip/hip_runtime.h>
#include <math.h>
#include <stdint.h>

#define BB 4
#define NN 1024
#define CC 768
#define HH 12
#define DH 64
#define KTOP 16

// Margin gate (proven constants): fast path iff fp32 gap > GATE.
#define GATE     2e-4f
#define SUPERSET 4e-4f

typedef __attribute__((ext_vector_type(8))) short short8v;
typedef __attribute__((ext_vector_type(4))) short short4v;
typedef __attribute__((ext_vector_type(4))) float f32x4;

// split f into bf16 hi + bf16 lo (lo = rn_bf16(f - hi)); returns {hi, lo}
__device__ __forceinline__ short2 bf16split(float f) {
    uint32_t u = __float_as_uint(f);
    uint32_t hb = (u + 0x8000u) & 0xFFFF0000u;
    float hf = __uint_as_float(hb);
    float lo = f - hf;
    short2 r;
    r.x = (short)(hb >> 16);
    r.y = (short)((__float_as_uint(lo) + 0x8000u) >> 16);
    return r;
}

__device__ __forceinline__ short8v lds_load8(const short* p) {
    short4v a = *(const short4v*)p;
    short4v b = *(const short4v*)(p + 4);
    short8v r;
    r[0] = a[0]; r[1] = a[1]; r[2] = a[2]; r[3] = a[3];
    r[4] = b[0]; r[5] = b[1]; r[6] = b[2]; r[7] = b[3];
    return r;
}

__device__ __forceinline__ uint32_t f2su(float f) {
    uint32_t u = __float_as_uint(f);
    return u ^ ((u & 0x80000000u) ? 0xFFFFFFFFu : 0x80000000u);
}
__device__ __forceinline__ float su2f(uint32_t s) {
    uint32_t u = s ^ ((s & 0x80000000u) ? 0x80000000u : 0xFFFFFFFFu);
    return __uint_as_float(u);
}

// ---------------- Kernel 1: QKV projection, inline split; writes SPLIT q/k ----------------
__global__ __launch_bounds__(256) void qkv_mfma(
    const float* __restrict__ x, const float* __restrict__ w,
    const float* __restrict__ bias,
    short* __restrict__ qh_g, short* __restrict__ ql_g,
    short* __restrict__ kh_g, short* __restrict__ kl_g,
    float* __restrict__ v32, int* __restrict__ wl_count) {
    __shared__ short xh[128][36], xl[128][36];   // 72B row stride: b64 conflict-free
    __shared__ short wh[64][36],  wl[64][36];
    const int tid = threadIdx.x;
    const int m0 = blockIdx.x * 128, n0 = blockIdx.y * 64;  // n0 in [0,2304)
    const int wave = tid >> 6, lane = tid & 63;
    const int wr = wave >> 1, wc = wave & 1;
    const int lr = lane & 15, lg = lane >> 4;

    if (blockIdx.x == 0 && blockIdx.y == 0 && tid == 0) *wl_count = 0;

    f32x4 acc[4][2];
#pragma unroll
    for (int i = 0; i < 4; ++i)
#pragma unroll
        for (int j = 0; j < 2; ++j) acc[i][j] = (f32x4)0.0f;

    for (int k0 = 0; k0 < CC; k0 += 32) {
        __syncthreads();
#pragma unroll
        for (int it = 0; it < 4; ++it) {
            int e = tid + 256 * it;
            int row = e >> 3, c4 = e & 7;
            float4 f = *reinterpret_cast<const float4*>(&x[(size_t)(m0 + row) * CC + k0 + 4 * c4]);
            short4v hv, lv;
            short2 s0 = bf16split(f.x); short2 s1 = bf16split(f.y);
            short2 s2 = bf16split(f.z); short2 s3 = bf16split(f.w);
            hv[0] = s0.x; lv[0] = s0.y; hv[1] = s1.x; lv[1] = s1.y;
            hv[2] = s2.x; lv[2] = s2.y; hv[3] = s3.x; lv[3] = s3.y;
            *(short4v*)&xh[row][4 * c4] = hv;
            *(short4v*)&xl[row][4 * c4] = lv;
        }
#pragma unroll
        for (int it = 0; it < 2; ++it) {
            int e = tid + 256 * it;
            int row = e >> 3, c4 = e & 7;
            float4 f = *reinterpret_cast<const float4*>(&w[(size_t)(n0 + row) * CC + k0 + 4 * c4]);
            short4v hv, lv;
            short2 s0 = bf16split(f.x); short2 s1 = bf16split(f.y);
            short2 s2 = bf16split(f.z); short2 s3 = bf16split(f.w);
            hv[0] = s0.x; lv[0] = s0.y; hv[1] = s1.x; lv[1] = s1.y;
            hv[2] = s2.x; lv[2] = s2.y; hv[3] = s3.x; lv[3] = s3.y;
            *(short4v*)&wh[row][4 * c4] = hv;
            *(short4v*)&wl[row][4 * c4] = lv;
        }
        __syncthreads();

        short8v ah[4], al[4], bh[2], bl[2];
#pragma unroll
        for (int mt = 0; mt < 4; ++mt) {
            int row = wr * 64 + mt * 16 + lr;
            ah[mt] = lds_load8(&xh[row][lg * 8]);
            al[mt] = lds_load8(&xl[row][lg * 8]);
        }
#pragma unroll
        for (int nt = 0; nt < 2; ++nt) {
            int col = wc * 32 + nt * 16 + lr;
            bh[nt] = lds_load8(&wh[col][lg * 8]);
            bl[nt] = lds_load8(&wl[col][lg * 8]);
        }
#pragma unroll
        for (int mt = 0; mt < 4; ++mt) {
#pragma unroll
            for (int nt = 0; nt < 2; ++nt) {
                acc[mt][nt] = __builtin_amdgcn_mfma_f32_16x16x32_bf16(ah[mt], bh[nt], acc[mt][nt], 0, 0, 0);
                acc[mt][nt] = __builtin_amdgcn_mfma_f32_16x16x32_bf16(ah[mt], bl[nt], acc[mt][nt], 0, 0, 0);
                acc[mt][nt] = __builtin_amdgcn_mfma_f32_16x16x32_bf16(al[mt], bh[nt], acc[mt][nt], 0, 0, 0);
            }
        }
    }

    const int t = n0 / CC;
#pragma unroll
    for (int mt = 0; mt < 4; ++mt) {
#pragma unroll
        for (int nt = 0; nt < 2; ++nt) {
#pragma unroll
            for (int r = 0; r < 4; ++r) {
                int m = m0 + wr * 64 + mt * 16 + lg * 4 + r;
                int col = n0 + wc * 32 + nt * 16 + lr;
                float val = acc[mt][nt][r] + bias[col];
                int rem = col - t * CC;
                int h = rem >> 6, d = rem & 63;
                int b = m >> 10, n = m & 1023;
                size_t off = (((size_t)(b * HH + h)) * NN + n) * DH + d;
                if (t == 0) {
                    short2 s = bf16split(val * 0.125f);   // exact pow2 pre-scale
                    qh_g[off] = s.x; ql_g[off] = s.y;
                } else if (t == 1) {
                    short2 s = bf16split(val);
                    kh_g[off] = s.x; kl_g[off] = s.y;
                } else {
                    v32[off] = val;
                }
            }
        }
    }
}

// ---------------- Kernel 2: FUSED scores (split-bf16 MFMA) + per-row top-16 ----------------
// Phase A: compute 64 rows x 1024 cols raw scores into attn_out (block-local region).
// Phase B: per-row selection (1 wave per row, 16 rows/wave) — identical logic to R18.
__global__ __launch_bounds__(256) void scores_topk(
    const short* __restrict__ qh_g, const short* __restrict__ ql_g,
    const short* __restrict__ kh_g, const short* __restrict__ kl_g,
    const float* __restrict__ v32,
    float* __restrict__ attn_out, float* __restrict__ xatt,
    int* __restrict__ wl_count, int* __restrict__ wl_row, int* __restrict__ wl_cand) {
    __shared__ short qh[64][68], ql[64][68];     // 136B row stride: b64 conflict-free
    __shared__ short kh[128][68], kl[128][68];
    __shared__ int      cand_idx[4][64];
    __shared__ uint32_t cand_val[4][64];
    const int bh = blockIdx.y;
    const int m0 = blockIdx.x * 64;
    const int tid = threadIdx.x;
    const int wave = tid >> 6, lane = tid & 63;
    const int lr = lane & 15, lg = lane >> 4;

    const size_t qbase = ((size_t)bh * NN + m0) * DH;
    const size_t kbase = (size_t)bh * NN * DH;

    // ---------- Phase A: scores ----------
#pragma unroll
    for (int it = 0; it < 2; ++it) {
        int e = tid + 256 * it;
        int row = e >> 3, c8 = (e & 7) << 3;
        size_t g = qbase + (size_t)row * DH + c8;
        *(short4v*)&qh[row][c8]     = *(const short4v*)&qh_g[g];
        *(short4v*)&qh[row][c8 + 4] = *(const short4v*)&qh_g[g + 4];
        *(short4v*)&ql[row][c8]     = *(const short4v*)&ql_g[g];
        *(short4v*)&ql[row][c8 + 4] = *(const short4v*)&ql_g[g + 4];
    }
    __syncthreads();

    short8v ahf[4][2], alf[4][2];
#pragma unroll
    for (int mt = 0; mt < 4; ++mt)
#pragma unroll
        for (int ks = 0; ks < 2; ++ks) {
            ahf[mt][ks] = lds_load8(&qh[mt * 16 + lr][ks * 32 + lg * 8]);
            alf[mt][ks] = lds_load8(&ql[mt * 16 + lr][ks * 32 + lg * 8]);
        }

    float* orow0 = attn_out + ((size_t)bh * NN + m0) * NN;

    for (int c0 = 0; c0 < NN; c0 += 128) {
        __syncthreads();
#pragma unroll
        for (int it = 0; it < 4; ++it) {
            int e = tid + 256 * it;
            int row = e >> 3, c8 = (e & 7) << 3;
            size_t g = kbase + (size_t)(c0 + row) * DH + c8;
            *(short4v*)&kh[row][c8]     = *(const short4v*)&kh_g[g];
            *(short4v*)&kh[row][c8 + 4] = *(const short4v*)&kh_g[g + 4];
            *(short4v*)&kl[row][c8]     = *(const short4v*)&kl_g[g];
            *(short4v*)&kl[row][c8 + 4] = *(const short4v*)&kl_g[g + 4];
        }
        __syncthreads();

        short8v bhf[2][2], blf[2][2];
#pragma unroll
        for (int nt = 0; nt < 2; ++nt)
#pragma unroll
            for (int ks = 0; ks < 2; ++ks) {
                int col = wave * 32 + nt * 16 + lr;
                bhf[nt][ks] = lds_load8(&kh[col][ks * 32 + lg * 8]);
                blf[nt][ks] = lds_load8(&kl[col][ks * 32 + lg * 8]);
            }

        f32x4 acc[4][2];
#pragma unroll
        for (int mt = 0; mt < 4; ++mt)
#pragma unroll
            for (int nt = 0; nt < 2; ++nt) acc[mt][nt] = (f32x4)0.0f;

#pragma unroll
        for (int mt = 0; mt < 4; ++mt)
#pragma unroll
            for (int nt = 0; nt < 2; ++nt)
#pragma unroll
                for (int ks = 0; ks < 2; ++ks) {
                    acc[mt][nt] = __builtin_amdgcn_mfma_f32_16x16x32_bf16(ahf[mt][ks], bhf[nt][ks], acc[mt][nt], 0, 0, 0);
                    acc[mt][nt] = __builtin_amdgcn_mfma_f32_16x16x32_bf16(ahf[mt][ks], blf[nt][ks], acc[mt][nt], 0, 0, 0);
                    acc[mt][nt] = __builtin_amdgcn_mfma_f32_16x16x32_bf16(alf[mt][ks], bhf[nt][ks], acc[mt][nt], 0, 0, 0);
                }

#pragma unroll
        for (int mt = 0; mt < 4; ++mt)
#pragma unroll
            for (int nt = 0; nt < 2; ++nt)
#pragma unroll
                for (int r = 0; r < 4; ++r)
                    orow0[(size_t)(mt * 16 + lg * 4 + r) * NN + c0 + wave * 32 + nt * 16 + lr] = acc[mt][nt][r];
    }

    // all score stores complete & visible to the block
    asm volatile("s_waitcnt vmcnt(0)" ::: "memory");
    __syncthreads();

    // ---------- Phase B: per-row top-16 (1 wave per row, 16 rows per wave) ----------
    for (int rr = 0; rr < 16; ++rr) {
        const int qn = m0 + wave * 16 + rr;
        float* srow = attn_out + ((size_t)bh * NN + qn) * NN;

        uint32_t su[16];
#pragma unroll
        for (int i = 0; i < 4; ++i) {
            float4 t4 = *(const float4*)&srow[i * 256 + lane * 4];
            su[4 * i + 0] = f2su(t4.x); su[4 * i + 1] = f2su(t4.y);
            su[4 * i + 2] = f2su(t4.z); su[4 * i + 3] = f2su(t4.w);
        }

        uint32_t thr = 0;
        for (int b = 31; b >= 0; --b) {
            uint32_t test = thr | (1u << b);
            int cnt = 0;
#pragma unroll
            for (int r = 0; r < 16; ++r)
                cnt += __popcll(__ballot(su[r] >= test));
            if (cnt >= 17) { thr = test; if (cnt <= 64) break; }
        }

        int C = 0;
#pragma unroll
        for (int r = 0; r < 16; ++r) {
            bool pr = (su[r] >= thr);
            unsigned long long mask = __ballot(pr);
            if (pr) {
                int pos = C + __popcll(mask & ((1ull << lane) - 1ull));
                if (pos < 64) {
                    cand_idx[wave][pos] = ((r >> 2) << 8) + (lane << 2) + (r & 3);
                    cand_val[wave][pos] = su[r];
                }
            }
            C += __popcll(mask);
        }
        if (C > 64) C = 64;

        uint32_t key = (lane < C) ? cand_val[wave][lane] : 0u;
        int      idx = (lane < C) ? cand_idx[wave][lane] : (0x40000000 + lane);

#pragma unroll
        for (int k = 2; k <= 64; k <<= 1) {
#pragma unroll
            for (int j = k >> 1; j > 0; j >>= 1) {
                uint32_t ok = __shfl_xor(key, j);
                int      oi = __shfl_xor(idx, j);
                bool mine_better = (key > ok) || (key == ok && idx < oi);
                bool lower = ((lane & j) == 0);
                bool dir_desc = ((lane & k) == 0);
                bool keep = dir_desc ? (lower ? mine_better : !mine_better)
                                     : (lower ? !mine_better : mine_better);
                if (!keep) { key = ok; idx = oi; }
            }
        }

        float f = su2f(key);
        float f15 = __shfl(f, 15);
        float f16 = __shfl(f, 16);

        bool fast = (f15 - f16 > GATE);
        float p = 0.0f;
        int selIdx = idx;

        if (fast) {
            float m = __shfl(f, 0);
            float e = (lane < KTOP) ? expf(f - m) : 0.0f;
            float sum = e;
#pragma unroll
            for (int off = 32; off; off >>= 1) sum += __shfl_xor(sum, off);
            p = e / sum;
        } else {
            uint32_t thr2 = f2su(f15 - SUPERSET);
            int C2 = 0;
#pragma unroll
            for (int r = 0; r < 16; ++r) {
                bool pr = (su[r] >= thr2);
                unsigned long long mask = __ballot(pr);
                if (pr) {
                    int pos = C2 + __popcll(mask & ((1ull << lane) - 1ull));
                    if (pos < 64) cand_idx[wave][pos] = ((r >> 2) << 8) + (lane << 2) + (r & 3);
                }
                C2 += __popcll(mask);
            }
            if (C2 > 64) C2 = 64;

            int slot = 0;
            if (lane == 0) slot = atomicAdd(wl_count, 1);
            slot = __shfl(slot, 0);
            int rowid = (bh << 10) | qn;
            if (lane == 0) wl_row[slot] = rowid | (C2 << 20);
            if (lane < C2) wl_cand[(size_t)slot * 64 + lane] = cand_idx[wave][lane];
        }

        // zero-fill row; fast rows also AV+scatter+xatt
#pragma unroll
        for (int i = 0; i < 4; ++i) {
            float4 z = make_float4(0.f, 0.f, 0.f, 0.f);
            *(float4*)&srow[i * 256 + lane * 4] = z;
        }

        if (fast) {
            const float* vb = v32 + (size_t)bh * NN * DH;
            float o = 0.0f;
#pragma unroll
            for (int t = 0; t < KTOP; ++t) {
                int jt = __shfl(selIdx, t);
                float pt = __shfl(p, t);
                o = fmaf(pt, vb[(size_t)jt * DH + lane], o);
            }
            asm volatile("s_waitcnt vmcnt(0)" ::: "memory");
            if (lane < KTOP) srow[selIdx] = p;
            int b = bh / HH, h = bh - b * HH;
            xatt[((size_t)b * NN + qn) * CC + h * DH + lane] = o;
        }
    }
}

// ---------------- Kernel 2c: slow rows — z = W_k^T q64 trick (exact fp64 from x,W) ------
__global__ __launch_bounds__(64) void slow_rescore(
    const float* __restrict__ x, const float* __restrict__ w_in,
    const float* __restrict__ b_in, const float* __restrict__ v32,
    const int* __restrict__ wl_count, const int* __restrict__ wl_row,
    const int* __restrict__ wl_cand,
    float* __restrict__ attn_out, float* __restrict__ xatt) {
    __shared__ double part[64][65];
    __shared__ double q_sh[64];
    const int lane = threadIdx.x;
    const int count = wl_count[0];

    for (int it = blockIdx.x; it < count; it += gridDim.x) {
        int ent = wl_row[it];
        int rowid = ent & 0xFFFF;
        int C2 = (ent >> 20) & 0x7F;
        int bh = rowid >> 10, qn = rowid & 1023;
        int bq = bh / HH, hq = bh - bq * HH;

        __syncthreads();

        const float* xq = x + ((size_t)bq * NN + qn) * CC;
        double xqd[12];
#pragma unroll
        for (int c = 0; c < 3; ++c) {
            float4 v = *(const float4*)&xq[c * 256 + 4 * lane];
            xqd[4 * c + 0] = v.x; xqd[4 * c + 1] = v.y;
            xqd[4 * c + 2] = v.z; xqd[4 * c + 3] = v.w;
        }
        const float* wqb = w_in + (size_t)(hq * DH) * CC;
        for (int r = 0; r < 64; ++r) {
            const float* wr = wqb + (size_t)r * CC;
            double s = 0.0;
#pragma unroll
            for (int c = 0; c < 3; ++c) {
                float4 v = *(const float4*)&wr[c * 256 + 4 * lane];
                s = fma((double)v.x, xqd[4 * c + 0], s);
                s = fma((double)v.y, xqd[4 * c + 1], s);
                s = fma((double)v.z, xqd[4 * c + 2], s);
                s = fma((double)v.w, xqd[4 * c + 3], s);
            }
            part[r][lane] = s;
        }
        __syncthreads();
        double q64 = 0.0, q64b = 0.0;
#pragma unroll
        for (int l = 0; l < 64; l += 2) { q64 += part[lane][l]; q64b += part[lane][l + 1]; }
        q64 += q64b + (double)b_in[hq * DH + lane];
        q_sh[lane] = q64;
        __syncthreads();

        double beta = q64 * (double)b_in[CC + hq * DH + lane];
#pragma unroll
        for (int off = 32; off; off >>= 1) beta += __shfl_xor(beta, off);

        const float* wkb = w_in + (size_t)(CC + hq * DH) * CC;
        double zd[12];
#pragma unroll
        for (int j = 0; j < 12; ++j) zd[j] = 0.0;
        for (int r = 0; r < 64; ++r) {
            double qr = q_sh[r];
            const float* wr = wkb + (size_t)r * CC;
#pragma unroll
            for (int c = 0; c < 3; ++c) {
                float4 v = *(const float4*)&wr[c * 256 + 4 * lane];
                zd[4 * c + 0] = fma(qr, (double)v.x, zd[4 * c + 0]);
                zd[4 * c + 1] = fma(qr, (double)v.y, zd[4 * c + 1]);
                zd[4 * c + 2] = fma(qr, (double)v.z, zd[4 * c + 2]);
                zd[4 * c + 3] = fma(qr, (double)v.w, zd[4 * c + 3]);
            }
        }

        double myS = -1.0e300;
        int myI = (1 << 30);
        for (int t = 0; t < C2; ++t) {
            int jt = wl_cand[(size_t)it * 64 + t];
            const float* xk = x + ((size_t)bq * NN + jt) * CC;
            double pr = 0.0;
#pragma unroll
            for (int c = 0; c < 3; ++c) {
                float4 v = *(const float4*)&xk[c * 256 + 4 * lane];
                pr = fma(zd[4 * c + 0], (double)v.x, pr);
                pr = fma(zd[4 * c + 1], (double)v.y, pr);
                pr = fma(zd[4 * c + 2], (double)v.z, pr);
                pr = fma(zd[4 * c + 3], (double)v.w, pr);
            }
#pragma unroll
            for (int off = 32; off; off >>= 1) pr += __shfl_xor(pr, off);
            if (lane == t) { myS = (pr + beta) * 0.125; myI = jt; }
        }

        double sS = myS;
        int sI = myI;
        double selS = 0.0; int selIdx = 0;
#pragma unroll 1
        for (int t = 0; t < KTOP; ++t) {
            double bv = sS; int bi = sI;
#pragma unroll
            for (int off = 32; off; off >>= 1) {
                double ov = __shfl_xor(bv, off);
                int oi = __shfl_xor(bi, off);
                if (ov > bv || (ov == bv && oi < bi)) { bv = ov; bi = oi; }
            }
            if (lane == t) { selS = bv; selIdx = bi; }
            if (sI == bi) sS = -1.0e300;
        }

        double m = __shfl(selS, 0);
        float e = (lane < KTOP) ? expf((float)(selS - m)) : 0.0f;
        float sum = e;
#pragma unroll
        for (int off = 32; off; off >>= 1) sum += __shfl_xor(sum, off);
        float p = e / sum;

        const float* vb = v32 + (size_t)bh * NN * DH;
        float o = 0.0f;
#pragma unroll
        for (int t = 0; t < KTOP; ++t) {
            int jt = __shfl(selIdx, t);
            float pt = __shfl(p, t);
            o = fmaf(pt, vb[(size_t)jt * DH + lane], o);
        }

        float* srow = attn_out + (size_t)rowid * NN;
        if (lane < KTOP) srow[selIdx] = p;
        xatt[((size_t)bq * NN + qn) * CC + hq * DH + lane] = o;
    }
}

// ---------------- Kernel 3: output projection via split-bf16 MFMA ----------------
__global__ __launch_bounds__(256) void out_proj_mfma(
    const float* __restrict__ a, const float* __restrict__ w,
    const float* __restrict__ bias, float* __restrict__ out) {
    __shared__ short xh[128][36], xl[128][36];
    __shared__ short wh[64][36],  wl[64][36];
    const int tid = threadIdx.x;
    const int m0 = blockIdx.x * 128, n0 = blockIdx.y * 64;  // n0 in [0,768)
    const int wave = tid >> 6, lane = tid & 63;
    const int wr = wave >> 1, wc = wave & 1;
    const int lr = lane & 15, lg = lane >> 4;

    f32x4 acc[4][2];
#pragma unroll
    for (int i = 0; i < 4; ++i)
#pragma unroll
        for (int j = 0; j < 2; ++j) acc[i][j] = (f32x4)0.0f;

    for (int k0 = 0; k0 < CC; k0 += 32) {
        __syncthreads();
#pragma unroll
        for (int it = 0; it < 4; ++it) {
            int e = tid + 256 * it;
            int row = e >> 3, c4 = e & 7;
            float4 f = *reinterpret_cast<const float4*>(&a[(size_t)(m0 + row) * CC + k0 + 4 * c4]);
            short4v hv, lv;
            short2 s0 = bf16split(f.x); short2 s1 = bf16split(f.y);
            short2 s2 = bf16split(f.z); short2 s3 = bf16split(f.w);
            hv[0] = s0.x; lv[0] = s0.y; hv[1] = s1.x; lv[1] = s1.y;
            hv[2] = s2.x; lv[2] = s2.y; hv[3] = s3.x; lv[3] = s3.y;
            *(short4v*)&xh[row][4 * c4] = hv;
            *(short4v*)&xl[row][4 * c4] = lv;
        }
#pragma unroll
        for (int it = 0; it < 2; ++it) {
            int e = tid + 256 * it;
            int row = e >> 3, c4 = e & 7;
            float4 f = *reinterpret_cast<const float4*>(&w[(size_t)(n0 + row) * CC + k0 + 4 * c4]);
            short4v hv, lv;
            short2 s0 = bf16split(f.x); short2 s1 = bf16split(f.y);
            short2 s2 = bf16split(f.z); short2 s3 = bf16split(f.w);
            hv[0] = s0.x; lv[0] = s0.y; hv[1] = s1.x; lv[1] = s1.y;
            hv[2] = s2.x; lv[2] = s2.y; hv[3] = s3.x; lv[3] = s3.y;
            *(short4v*)&wh[row][4 * c4] = hv;
            *(short4v*)&wl[row][4 * c4] = lv;
        }
        __syncthreads();

        short8v ah[4], al[4], bh[2], bl[2];
#pragma unroll
        for (int mt = 0; mt < 4; ++mt) {
            int row = wr * 64 + mt * 16 + lr;
            ah[mt] = lds_load8(&xh[row][lg * 8]);
            al[mt] = lds_load8(&xl[row][lg * 8]);
        }
#pragma unroll
        for (int nt = 0; nt < 2; ++nt) {
            int col = wc * 32 + nt * 16 + lr;
            bh[nt] = lds_load8(&wh[col][lg * 8]);
            bl[nt] = lds_load8(&wl[col][lg * 8]);
        }
#pragma unroll
        for (int mt = 0; mt < 4; ++mt) {
#pragma unroll
            for (int nt = 0; nt < 2; ++nt) {
                acc[mt][nt] = __builtin_amdgcn_mfma_f32_16x16x32_bf16(ah[mt], bh[nt], acc[mt][nt], 0, 0, 0);
                acc[mt][nt] = __builtin_amdgcn_mfma_f32_16x16x32_bf16(ah[mt], bl[nt], acc[mt][nt], 0, 0, 0);
                acc[mt][nt] = __builtin_amdgcn_mfma_f32_16x16x32_bf16(al[mt], bh[nt], acc[mt][nt], 0, 0, 0);
            }
        }
    }

#pragma unroll
    for (int mt = 0; mt < 4; ++mt) {
#pragma unroll
        for (int nt = 0; nt < 2; ++nt) {
#pragma unroll
            for (int r = 0; r < 4; ++r) {
                int m = m0 + wr * 64 + mt * 16 + lg * 4 + r;
                int col = n0 + wc * 32 + nt * 16 + lr;
                out[(size_t)m * CC + col] = acc[mt][nt][r] + bias[col];
            }
        }
    }
}

extern "C" void kernel_launch(void* const* d_in, const int* in_sizes, int n_in,
                              void* d_out, int out_size, void* d_ws, size_t ws_size,
                              hipStream_t stream) {
    const float* x     = (const float*)d_in[0];
    const float* w_in  = (const float*)d_in[1];
    const float* b_in  = (const float*)d_in[2];
    const float* w_out = (const float*)d_in[3];
    const float* b_out = (const float*)d_in[4];

    float* xout     = (float*)d_out;                        // [B][N][C]
    float* attn_out = (float*)d_out + (size_t)BB * NN * CC; // [B][H][N][N]

    char* ws = (char*)d_ws;
    short* qh_g = (short*)(ws);                              //  6,291,456 B
    short* ql_g = (short*)(ws + 6291456);                    //  6,291,456 B
    short* kh_g = (short*)(ws + 12582912);                   //  6,291,456 B
    short* kl_g = (short*)(ws + 18874368);                   //  6,291,456 B
    float* v32  = (float*)(ws + 25165824);                   // 12,582,912 B
    float* xatt = (float*)(ws + 37748736);                   // 12,582,912 B
    int* wl_count = (int*)(ws + 50331648);                   // 4 B (pad 256)
    int* wl_row   = (int*)(ws + 50331904);                   // 196,608 B
    int* wl_cand  = (int*)(ws + 50528512);                   // 12,582,912 B

    hipLaunchKernelGGL(qkv_mfma, dim3(32, 36), dim3(256), 0, stream,
                       x, w_in, b_in, qh_g, ql_g, kh_g, kl_g, v32, wl_count);
    hipLaunchKernelGGL(scores_topk, dim3(NN / 64, BB * HH), dim3(256), 0, stream,
                       qh_g, ql_g, kh_g, kl_g, v32, attn_out, xatt, wl_count, wl_row, wl_cand);
    hipLaunchKernelGGL(slow_rescore, dim3(1024), dim3(64), 0, stream,
                       x, w_in, b_in, v32, wl_count, wl_row, wl_cand, attn_out, xatt);
    hipLaunchKernelGGL(out_proj_mfma, dim3(32, 12), dim3(256), 0, stream,
                       xatt, w_out, b_out, xout);
}

// Round 20
// 337.951 us; speedup vs baseline: 1.3430x; 1.3430x over previous
//
#include <hip/hip_runtime.h>
#include <math.h>
#include <stdint.h>

#define BB 4
#define NN 1024
#define CC 768
#define HH 12
#define DH 64
#define KTOP 16

// Margin gate (proven constants): fast path iff fp32 gap > GATE.
#define GATE     2e-4f
#define SUPERSET 4e-4f

typedef __attribute__((ext_vector_type(8))) short short8v;
typedef __attribute__((ext_vector_type(4))) short short4v;
typedef __attribute__((ext_vector_type(4))) float f32x4;

// split f into bf16 hi + bf16 lo (lo = rn_bf16(f - hi)); returns {hi, lo}
__device__ __forceinline__ short2 bf16split(float f) {
    uint32_t u = __float_as_uint(f);
    uint32_t hb = (u + 0x8000u) & 0xFFFF0000u;
    float hf = __uint_as_float(hb);
    float lo = f - hf;
    short2 r;
    r.x = (short)(hb >> 16);
    r.y = (short)((__float_as_uint(lo) + 0x8000u) >> 16);
    return r;
}

__device__ __forceinline__ short8v lds_load8(const short* p) {
    short4v a = *(const short4v*)p;
    short4v b = *(const short4v*)(p + 4);
    short8v r;
    r[0] = a[0]; r[1] = a[1]; r[2] = a[2]; r[3] = a[3];
    r[4] = b[0]; r[5] = b[1]; r[6] = b[2]; r[7] = b[3];
    return r;
}

// ---------------- Kernel 1: QKV projection, inline split; writes SPLIT q/k ----------------
__global__ __launch_bounds__(256) void qkv_mfma(
    const float* __restrict__ x, const float* __restrict__ w,
    const float* __restrict__ bias,
    short* __restrict__ qh_g, short* __restrict__ ql_g,
    short* __restrict__ kh_g, short* __restrict__ kl_g,
    float* __restrict__ v32, int* __restrict__ wl_count) {
    __shared__ short xh[128][36], xl[128][36];   // 72B row stride: b64 conflict-free
    __shared__ short wh[64][36],  wl[64][36];
    const int tid = threadIdx.x;
    const int m0 = blockIdx.x * 128, n0 = blockIdx.y * 64;  // n0 in [0,2304)
    const int wave = tid >> 6, lane = tid & 63;
    const int wr = wave >> 1, wc = wave & 1;
    const int lr = lane & 15, lg = lane >> 4;

    if (blockIdx.x == 0 && blockIdx.y == 0 && tid == 0) *wl_count = 0;

    f32x4 acc[4][2];
#pragma unroll
    for (int i = 0; i < 4; ++i)
#pragma unroll
        for (int j = 0; j < 2; ++j) acc[i][j] = (f32x4)0.0f;

    for (int k0 = 0; k0 < CC; k0 += 32) {
        __syncthreads();
#pragma unroll
        for (int it = 0; it < 4; ++it) {
            int e = tid + 256 * it;
            int row = e >> 3, c4 = e & 7;
            float4 f = *reinterpret_cast<const float4*>(&x[(size_t)(m0 + row) * CC + k0 + 4 * c4]);
            short4v hv, lv;
            short2 s0 = bf16split(f.x); short2 s1 = bf16split(f.y);
            short2 s2 = bf16split(f.z); short2 s3 = bf16split(f.w);
            hv[0] = s0.x; lv[0] = s0.y; hv[1] = s1.x; lv[1] = s1.y;
            hv[2] = s2.x; lv[2] = s2.y; hv[3] = s3.x; lv[3] = s3.y;
            *(short4v*)&xh[row][4 * c4] = hv;
            *(short4v*)&xl[row][4 * c4] = lv;
        }
#pragma unroll
        for (int it = 0; it < 2; ++it) {
            int e = tid + 256 * it;
            int row = e >> 3, c4 = e & 7;
            float4 f = *reinterpret_cast<const float4*>(&w[(size_t)(n0 + row) * CC + k0 + 4 * c4]);
            short4v hv, lv;
            short2 s0 = bf16split(f.x); short2 s1 = bf16split(f.y);
            short2 s2 = bf16split(f.z); short2 s3 = bf16split(f.w);
            hv[0] = s0.x; lv[0] = s0.y; hv[1] = s1.x; lv[1] = s1.y;
            hv[2] = s2.x; lv[2] = s2.y; hv[3] = s3.x; lv[3] = s3.y;
            *(short4v*)&wh[row][4 * c4] = hv;
            *(short4v*)&wl[row][4 * c4] = lv;
        }
        __syncthreads();

        short8v ah[4], al[4], bh[2], bl[2];
#pragma unroll
        for (int mt = 0; mt < 4; ++mt) {
            int row = wr * 64 + mt * 16 + lr;
            ah[mt] = lds_load8(&xh[row][lg * 8]);
            al[mt] = lds_load8(&xl[row][lg * 8]);
        }
#pragma unroll
        for (int nt = 0; nt < 2; ++nt) {
            int col = wc * 32 + nt * 16 + lr;
            bh[nt] = lds_load8(&wh[col][lg * 8]);
            bl[nt] = lds_load8(&wl[col][lg * 8]);
        }
#pragma unroll
        for (int mt = 0; mt < 4; ++mt) {
#pragma unroll
            for (int nt = 0; nt < 2; ++nt) {
                acc[mt][nt] = __builtin_amdgcn_mfma_f32_16x16x32_bf16(ah[mt], bh[nt], acc[mt][nt], 0, 0, 0);
                acc[mt][nt] = __builtin_amdgcn_mfma_f32_16x16x32_bf16(ah[mt], bl[nt], acc[mt][nt], 0, 0, 0);
                acc[mt][nt] = __builtin_amdgcn_mfma_f32_16x16x32_bf16(al[mt], bh[nt], acc[mt][nt], 0, 0, 0);
            }
        }
    }

    const int t = n0 / CC;
#pragma unroll
    for (int mt = 0; mt < 4; ++mt) {
#pragma unroll
        for (int nt = 0; nt < 2; ++nt) {
#pragma unroll
            for (int r = 0; r < 4; ++r) {
                int m = m0 + wr * 64 + mt * 16 + lg * 4 + r;
                int col = n0 + wc * 32 + nt * 16 + lr;
                float val = acc[mt][nt][r] + bias[col];
                int rem = col - t * CC;
                int h = rem >> 6, d = rem & 63;
                int b = m >> 10, n = m & 1023;
                size_t off = (((size_t)(b * HH + h)) * NN + n) * DH + d;
                if (t == 0) {
                    short2 s = bf16split(val * 0.125f);   // exact pow2 pre-scale
                    qh_g[off] = s.x; ql_g[off] = s.y;
                } else if (t == 1) {
                    short2 s = bf16split(val);
                    kh_g[off] = s.x; kl_g[off] = s.y;
                } else {
                    v32[off] = val;
                }
            }
        }
    }
}

// ---------------- Kernel 2a: scores via split-bf16 MFMA (pre-split q/k, copy staging) ----
__global__ __launch_bounds__(256) void scores_mfma(
    const short* __restrict__ qh_g, const short* __restrict__ ql_g,
    const short* __restrict__ kh_g, const short* __restrict__ kl_g,
    float* __restrict__ attn_out) {
    __shared__ short qh[64][68], ql[64][68];     // 136B row stride: b64 conflict-free
    __shared__ short kh[128][68], kl[128][68];
    const int bh = blockIdx.y;
    const int m0 = blockIdx.x * 64;
    const int tid = threadIdx.x;
    const int wave = tid >> 6, lane = tid & 63;
    const int lr = lane & 15, lg = lane >> 4;

    const size_t qbase = ((size_t)bh * NN + m0) * DH;
    const size_t kbase = (size_t)bh * NN * DH;

    // stage Q once: 64 rows x 64 shorts per buffer (pure copy)
#pragma unroll
    for (int it = 0; it < 2; ++it) {
        int e = tid + 256 * it;
        int row = e >> 3, c8 = (e & 7) << 3;
        size_t g = qbase + (size_t)row * DH + c8;
        *(short4v*)&qh[row][c8]     = *(const short4v*)&qh_g[g];
        *(short4v*)&qh[row][c8 + 4] = *(const short4v*)&qh_g[g + 4];
        *(short4v*)&ql[row][c8]     = *(const short4v*)&ql_g[g];
        *(short4v*)&ql[row][c8 + 4] = *(const short4v*)&ql_g[g + 4];
    }
    __syncthreads();

    // hoist A-fragments: 4 m-tiles x 2 k-steps, hi+lo
    short8v ah[4][2], al[4][2];
#pragma unroll
    for (int mt = 0; mt < 4; ++mt)
#pragma unroll
        for (int ks = 0; ks < 2; ++ks) {
            ah[mt][ks] = lds_load8(&qh[mt * 16 + lr][ks * 32 + lg * 8]);
            al[mt][ks] = lds_load8(&ql[mt * 16 + lr][ks * 32 + lg * 8]);
        }

    float* orow0 = attn_out + ((size_t)bh * NN + m0) * NN;

    for (int c0 = 0; c0 < NN; c0 += 128) {
        __syncthreads();
        // stage K chunk: 128 rows x 64 shorts per buffer (pure copy)
#pragma unroll
        for (int it = 0; it < 4; ++it) {
            int e = tid + 256 * it;
            int row = e >> 3, c8 = (e & 7) << 3;
            size_t g = kbase + (size_t)(c0 + row) * DH + c8;
            *(short4v*)&kh[row][c8]     = *(const short4v*)&kh_g[g];
            *(short4v*)&kh[row][c8 + 4] = *(const short4v*)&kh_g[g + 4];
            *(short4v*)&kl[row][c8]     = *(const short4v*)&kl_g[g];
            *(short4v*)&kl[row][c8 + 4] = *(const short4v*)&kl_g[g + 4];
        }
        __syncthreads();

        short8v bhf[2][2], blf[2][2];
#pragma unroll
        for (int nt = 0; nt < 2; ++nt)
#pragma unroll
            for (int ks = 0; ks < 2; ++ks) {
                int col = wave * 32 + nt * 16 + lr;
                bhf[nt][ks] = lds_load8(&kh[col][ks * 32 + lg * 8]);
                blf[nt][ks] = lds_load8(&kl[col][ks * 32 + lg * 8]);
            }

        f32x4 acc[4][2];
#pragma unroll
        for (int mt = 0; mt < 4; ++mt)
#pragma unroll
            for (int nt = 0; nt < 2; ++nt) acc[mt][nt] = (f32x4)0.0f;

#pragma unroll
        for (int mt = 0; mt < 4; ++mt)
#pragma unroll
            for (int nt = 0; nt < 2; ++nt)
#pragma unroll
                for (int ks = 0; ks < 2; ++ks) {
                    acc[mt][nt] = __builtin_amdgcn_mfma_f32_16x16x32_bf16(ah[mt][ks], bhf[nt][ks], acc[mt][nt], 0, 0, 0);
                    acc[mt][nt] = __builtin_amdgcn_mfma_f32_16x16x32_bf16(ah[mt][ks], blf[nt][ks], acc[mt][nt], 0, 0, 0);
                    acc[mt][nt] = __builtin_amdgcn_mfma_f32_16x16x32_bf16(al[mt][ks], bhf[nt][ks], acc[mt][nt], 0, 0, 0);
                }

#pragma unroll
        for (int mt = 0; mt < 4; ++mt)
#pragma unroll
            for (int nt = 0; nt < 2; ++nt)
#pragma unroll
                for (int r = 0; r < 4; ++r)
                    orow0[(size_t)(mt * 16 + lg * 4 + r) * NN + c0 + wave * 32 + nt * 16 + lr] = acc[mt][nt][r];
    }
}

// ---------------- Kernel 2b: bitonic top-16; slow rows -> worklist ----------------
__device__ __forceinline__ uint32_t f2su(float f) {
    uint32_t u = __float_as_uint(f);
    return u ^ ((u & 0x80000000u) ? 0xFFFFFFFFu : 0x80000000u);
}
__device__ __forceinline__ float su2f(uint32_t s) {
    uint32_t u = s ^ ((s & 0x80000000u) ? 0x80000000u : 0xFFFFFFFFu);
    return __uint_as_float(u);
}

__global__ __launch_bounds__(256) void topk_select(
    const float* __restrict__ v32,
    float* __restrict__ attn_out, float* __restrict__ xatt,
    int* __restrict__ wl_count, int* __restrict__ wl_row, int* __restrict__ wl_cand) {
    __shared__ int      cand_idx[4][64];
    __shared__ uint32_t cand_val[4][64];
    const int blk = blockIdx.x;
    const int wave = threadIdx.x >> 6, lane = threadIdx.x & 63;
    const int bh = blk >> 8;
    const int qn = ((blk & 255) << 2) | wave;

    float* srow = attn_out + ((size_t)bh * NN + qn) * NN;

    uint32_t su[16];
#pragma unroll
    for (int i = 0; i < 4; ++i) {
        float4 t = *(const float4*)&srow[i * 256 + lane * 4];
        su[4 * i + 0] = f2su(t.x); su[4 * i + 1] = f2su(t.y);
        su[4 * i + 2] = f2su(t.z); su[4 * i + 3] = f2su(t.w);
    }

    // binary search: largest thr with count(su >= thr) >= 17; early-exit in [17,64]
    uint32_t thr = 0;
    for (int b = 31; b >= 0; --b) {
        uint32_t test = thr | (1u << b);
        int cnt = 0;
#pragma unroll
        for (int r = 0; r < 16; ++r)
            cnt += __popcll(__ballot(su[r] >= test));
        if (cnt >= 17) { thr = test; if (cnt <= 64) break; }
    }

    int C = 0;
#pragma unroll
    for (int r = 0; r < 16; ++r) {
        bool pr = (su[r] >= thr);
        unsigned long long mask = __ballot(pr);
        if (pr) {
            int pos = C + __popcll(mask & ((1ull << lane) - 1ull));
            if (pos < 64) {
                cand_idx[wave][pos] = ((r >> 2) << 8) + (lane << 2) + (r & 3);
                cand_val[wave][pos] = su[r];
            }
        }
        C += __popcll(mask);
    }
    if (C > 64) C = 64;

    uint32_t key = (lane < C) ? cand_val[wave][lane] : 0u;
    int      idx = (lane < C) ? cand_idx[wave][lane] : (0x40000000 + lane);

    // bitonic sort 64 lanes: (key desc, idx asc)
#pragma unroll
    for (int k = 2; k <= 64; k <<= 1) {
#pragma unroll
        for (int j = k >> 1; j > 0; j >>= 1) {
            uint32_t ok = __shfl_xor(key, j);
            int      oi = __shfl_xor(idx, j);
            bool mine_better = (key > ok) || (key == ok && idx < oi);
            bool lower = ((lane & j) == 0);
            bool dir_desc = ((lane & k) == 0);
            bool keep = dir_desc ? (lower ? mine_better : !mine_better)
                                 : (lower ? !mine_better : mine_better);
            if (!keep) { key = ok; idx = oi; }
        }
    }

    float f = su2f(key);
    float f15 = __shfl(f, 15);
    float f16 = __shfl(f, 16);

    bool fast = (f15 - f16 > GATE);
    float p = 0.0f;
    int selIdx = idx;

    if (fast) {
        float m = __shfl(f, 0);
        float e = (lane < KTOP) ? expf(f - m) : 0.0f;
        float sum = e;
#pragma unroll
        for (int off = 32; off; off >>= 1) sum += __shfl_xor(sum, off);
        p = e / sum;
    } else {
        uint32_t thr2 = f2su(f15 - SUPERSET);
        int C2 = 0;
#pragma unroll
        for (int r = 0; r < 16; ++r) {
            bool pr = (su[r] >= thr2);
            unsigned long long mask = __ballot(pr);
            if (pr) {
                int pos = C2 + __popcll(mask & ((1ull << lane) - 1ull));
                if (pos < 64) cand_idx[wave][pos] = ((r >> 2) << 8) + (lane << 2) + (r & 3);
            }
            C2 += __popcll(mask);
        }
        if (C2 > 64) C2 = 64;

        int slot = 0;
        if (lane == 0) slot = atomicAdd(wl_count, 1);
        slot = __shfl(slot, 0);
        int rowid = (bh << 10) | qn;
        if (lane == 0) wl_row[slot] = rowid | (C2 << 20);
        if (lane < C2) wl_cand[(size_t)slot * 64 + lane] = cand_idx[wave][lane];
    }

    // zero-fill row (all rows); fast rows also AV+scatter+xatt
#pragma unroll
    for (int i = 0; i < 4; ++i) {
        float4 z = make_float4(0.f, 0.f, 0.f, 0.f);
        *(float4*)&srow[i * 256 + lane * 4] = z;
    }

    if (fast) {
        const float* vb = v32 + (size_t)bh * NN * DH;
        float o = 0.0f;
#pragma unroll
        for (int t = 0; t < KTOP; ++t) {
            int jt = __shfl(selIdx, t);
            float pt = __shfl(p, t);
            o = fmaf(pt, vb[(size_t)jt * DH + lane], o);
        }
        asm volatile("s_waitcnt vmcnt(0)" ::: "memory");
        if (lane < KTOP) srow[selIdx] = p;
        int b = bh / HH, h = bh - b * HH;
        xatt[((size_t)b * NN + qn) * CC + h * DH + lane] = o;
    }
}

// ---------------- Kernel 2c: slow rows — z = W_k^T q64 trick (exact fp64 from x,W) ------
__global__ __launch_bounds__(64) void slow_rescore(
    const float* __restrict__ x, const float* __restrict__ w_in,
    const float* __restrict__ b_in, const float* __restrict__ v32,
    const int* __restrict__ wl_count, const int* __restrict__ wl_row,
    const int* __restrict__ wl_cand,
    float* __restrict__ attn_out, float* __restrict__ xatt) {
    __shared__ double part[64][65];
    __shared__ double q_sh[64];
    const int lane = threadIdx.x;
    const int count = wl_count[0];

    for (int it = blockIdx.x; it < count; it += gridDim.x) {
        int ent = wl_row[it];
        int rowid = ent & 0xFFFF;
        int C2 = (ent >> 20) & 0x7F;
        int bh = rowid >> 10, qn = rowid & 1023;
        int bq = bh / HH, hq = bh - bq * HH;

        __syncthreads();

        const float* xq = x + ((size_t)bq * NN + qn) * CC;
        double xqd[12];
#pragma unroll
        for (int c = 0; c < 3; ++c) {
            float4 v = *(const float4*)&xq[c * 256 + 4 * lane];
            xqd[4 * c + 0] = v.x; xqd[4 * c + 1] = v.y;
            xqd[4 * c + 2] = v.z; xqd[4 * c + 3] = v.w;
        }
        const float* wqb = w_in + (size_t)(hq * DH) * CC;
        for (int r = 0; r < 64; ++r) {
            const float* wr = wqb + (size_t)r * CC;
            double s = 0.0;
#pragma unroll
            for (int c = 0; c < 3; ++c) {
                float4 v = *(const float4*)&wr[c * 256 + 4 * lane];
                s = fma((double)v.x, xqd[4 * c + 0], s);
                s = fma((double)v.y, xqd[4 * c + 1], s);
                s = fma((double)v.z, xqd[4 * c + 2], s);
                s = fma((double)v.w, xqd[4 * c + 3], s);
            }
            part[r][lane] = s;
        }
        __syncthreads();
        double q64 = 0.0, q64b = 0.0;
#pragma unroll
        for (int l = 0; l < 64; l += 2) { q64 += part[lane][l]; q64b += part[lane][l + 1]; }
        q64 += q64b + (double)b_in[hq * DH + lane];
        q_sh[lane] = q64;
        __syncthreads();

        double beta = q64 * (double)b_in[CC + hq * DH + lane];
#pragma unroll
        for (int off = 32; off; off >>= 1) beta += __shfl_xor(beta, off);

        const float* wkb = w_in + (size_t)(CC + hq * DH) * CC;
        double zd[12];
#pragma unroll
        for (int j = 0; j < 12; ++j) zd[j] = 0.0;
        for (int r = 0; r < 64; ++r) {
            double qr = q_sh[r];
            const float* wr = wkb + (size_t)r * CC;
#pragma unroll
            for (int c = 0; c < 3; ++c) {
                float4 v = *(const float4*)&wr[c * 256 + 4 * lane];
                zd[4 * c + 0] = fma(qr, (double)v.x, zd[4 * c + 0]);
                zd[4 * c + 1] = fma(qr, (double)v.y, zd[4 * c + 1]);
                zd[4 * c + 2] = fma(qr, (double)v.z, zd[4 * c + 2]);
                zd[4 * c + 3] = fma(qr, (double)v.w, zd[4 * c + 3]);
            }
        }

        double myS = -1.0e300;
        int myI = (1 << 30);
        for (int t = 0; t < C2; ++t) {
            int jt = wl_cand[(size_t)it * 64 + t];
            const float* xk = x + ((size_t)bq * NN + jt) * CC;
            double pr = 0.0;
#pragma unroll
            for (int c = 0; c < 3; ++c) {
                float4 v = *(const float4*)&xk[c * 256 + 4 * lane];
                pr = fma(zd[4 * c + 0], (double)v.x, pr);
                pr = fma(zd[4 * c + 1], (double)v.y, pr);
                pr = fma(zd[4 * c + 2], (double)v.z, pr);
                pr = fma(zd[4 * c + 3], (double)v.w, pr);
            }
#pragma unroll
            for (int off = 32; off; off >>= 1) pr += __shfl_xor(pr, off);
            if (lane == t) { myS = (pr + beta) * 0.125; myI = jt; }
        }

        double sS = myS;
        int sI = myI;
        double selS = 0.0; int selIdx = 0;
#pragma unroll 1
        for (int t = 0; t < KTOP; ++t) {
            double bv = sS; int bi = sI;
#pragma unroll
            for (int off = 32; off; off >>= 1) {
                double ov = __shfl_xor(bv, off);
                int oi = __shfl_xor(bi, off);
                if (ov > bv || (ov == bv && oi < bi)) { bv = ov; bi = oi; }
            }
            if (lane == t) { selS = bv; selIdx = bi; }
            if (sI == bi) sS = -1.0e300;
        }

        double m = __shfl(selS, 0);
        float e = (lane < KTOP) ? expf((float)(selS - m)) : 0.0f;
        float sum = e;
#pragma unroll
        for (int off = 32; off; off >>= 1) sum += __shfl_xor(sum, off);
        float p = e / sum;

        const float* vb = v32 + (size_t)bh * NN * DH;
        float o = 0.0f;
#pragma unroll
        for (int t = 0; t < KTOP; ++t) {
            int jt = __shfl(selIdx, t);
            float pt = __shfl(p, t);
            o = fmaf(pt, vb[(size_t)jt * DH + lane], o);
        }

        float* srow = attn_out + (size_t)rowid * NN;
        if (lane < KTOP) srow[selIdx] = p;
        xatt[((size_t)bq * NN + qn) * CC + hq * DH + lane] = o;
    }
}

// ---------------- Kernel 3: output projection via split-bf16 MFMA ----------------
__global__ __launch_bounds__(256) void out_proj_mfma(
    const float* __restrict__ a, const float* __restrict__ w,
    const float* __restrict__ bias, float* __restrict__ out) {
    __shared__ short xh[128][36], xl[128][36];
    __shared__ short wh[64][36],  wl[64][36];
    const int tid = threadIdx.x;
    const int m0 = blockIdx.x * 128, n0 = blockIdx.y * 64;  // n0 in [0,768)
    const int wave = tid >> 6, lane = tid & 63;
    const int wr = wave >> 1, wc = wave & 1;
    const int lr = lane & 15, lg = lane >> 4;

    f32x4 acc[4][2];
#pragma unroll
    for (int i = 0; i < 4; ++i)
#pragma unroll
        for (int j = 0; j < 2; ++j) acc[i][j] = (f32x4)0.0f;

    for (int k0 = 0; k0 < CC; k0 += 32) {
        __syncthreads();
#pragma unroll
        for (int it = 0; it < 4; ++it) {
            int e = tid + 256 * it;
            int row = e >> 3, c4 = e & 7;
            float4 f = *reinterpret_cast<const float4*>(&a[(size_t)(m0 + row) * CC + k0 + 4 * c4]);
            short4v hv, lv;
            short2 s0 = bf16split(f.x); short2 s1 = bf16split(f.y);
            short2 s2 = bf16split(f.z); short2 s3 = bf16split(f.w);
            hv[0] = s0.x; lv[0] = s0.y; hv[1] = s1.x; lv[1] = s1.y;
            hv[2] = s2.x; lv[2] = s2.y; hv[3] = s3.x; lv[3] = s3.y;
            *(short4v*)&xh[row][4 * c4] = hv;
            *(short4v*)&xl[row][4 * c4] = lv;
        }
#pragma unroll
        for (int it = 0; it < 2; ++it) {
            int e = tid + 256 * it;
            int row = e >> 3, c4 = e & 7;
            float4 f = *reinterpret_cast<const float4*>(&w[(size_t)(n0 + row) * CC + k0 + 4 * c4]);
            short4v hv, lv;
            short2 s0 = bf16split(f.x); short2 s1 = bf16split(f.y);
            short2 s2 = bf16split(f.z); short2 s3 = bf16split(f.w);
            hv[0] = s0.x; lv[0] = s0.y; hv[1] = s1.x; lv[1] = s1.y;
            hv[2] = s2.x; lv[2] = s2.y; hv[3] = s3.x; lv[3] = s3.y;
            *(short4v*)&wh[row][4 * c4] = hv;
            *(short4v*)&wl[row][4 * c4] = lv;
        }
        __syncthreads();

        short8v ah[4], al[4], bh[2], bl[2];
#pragma unroll
        for (int mt = 0; mt < 4; ++mt) {
            int row = wr * 64 + mt * 16 + lr;
            ah[mt] = lds_load8(&xh[row][lg * 8]);
            al[mt] = lds_load8(&xl[row][lg * 8]);
        }
#pragma unroll
        for (int nt = 0; nt < 2; ++nt) {
            int col = wc * 32 + nt * 16 + lr;
            bh[nt] = lds_load8(&wh[col][lg * 8]);
            bl[nt] = lds_load8(&wl[col][lg * 8]);
        }
#pragma unroll
        for (int mt = 0; mt < 4; ++mt) {
#pragma unroll
            for (int nt = 0; nt < 2; ++nt) {
                acc[mt][nt] = __builtin_amdgcn_mfma_f32_16x16x32_bf16(ah[mt], bh[nt], acc[mt][nt], 0, 0, 0);
                acc[mt][nt] = __builtin_amdgcn_mfma_f32_16x16x32_bf16(ah[mt], bl[nt], acc[mt][nt], 0, 0, 0);
                acc[mt][nt] = __builtin_amdgcn_mfma_f32_16x16x32_bf16(al[mt], bh[nt], acc[mt][nt], 0, 0, 0);
            }
        }
    }

#pragma unroll
    for (int mt = 0; mt < 4; ++mt) {
#pragma unroll
        for (int nt = 0; nt < 2; ++nt) {
#pragma unroll
            for (int r = 0; r < 4; ++r) {
                int m = m0 + wr * 64 + mt * 16 + lg * 4 + r;
                int col = n0 + wc * 32 + nt * 16 + lr;
                out[(size_t)m * CC + col] = acc[mt][nt][r] + bias[col];
            }
        }
    }
}

extern "C" void kernel_launch(void* const* d_in, const int* in_sizes, int n_in,
                              void* d_out, int out_size, void* d_ws, size_t ws_size,
                              hipStream_t stream) {
    const float* x     = (const float*)d_in[0];
    const float* w_in  = (const float*)d_in[1];
    const float* b_in  = (const float*)d_in[2];
    const float* w_out = (const float*)d_in[3];
    const float* b_out = (const float*)d_in[4];

    float* xout     = (float*)d_out;                        // [B][N][C]
    float* attn_out = (float*)d_out + (size_t)BB * NN * CC; // [B][H][N][N]

    char* ws = (char*)d_ws;
    short* qh_g = (short*)(ws);                              //  6,291,456 B
    short* ql_g = (short*)(ws + 6291456);                    //  6,291,456 B
    short* kh_g = (short*)(ws + 12582912);                   //  6,291,456 B
    short* kl_g = (short*)(ws + 18874368);                   //  6,291,456 B
    float* v32  = (float*)(ws + 25165824);                   // 12,582,912 B
    float* xatt = (float*)(ws + 37748736);                   // 12,582,912 B
    int* wl_count = (int*)(ws + 50331648);                   // 4 B (pad 256)
    int* wl_row   = (int*)(ws + 50331904);                   // 196,608 B
    int* wl_cand  = (int*)(ws + 50528512);                   // 12,582,912 B

    hipLaunchKernelGGL(qkv_mfma, dim3(32, 36), dim3(256), 0, stream,
                       x, w_in, b_in, qh_g, ql_g, kh_g, kl_g, v32, wl_count);
    hipLaunchKernelGGL(scores_mfma, dim3(NN / 64, BB * HH), dim3(256), 0, stream,
                       qh_g, ql_g, kh_g, kl_g, attn_out);
    hipLaunchKernelGGL(topk_select, dim3(BB * HH * (NN / 4)), dim3(256), 0, stream,
                       v32, attn_out, xatt, wl_count, wl_row, wl_cand);
    hipLaunchKernelGGL(slow_rescore, dim3(1024), dim3(64), 0, stream,
                       x, w_in, b_in, v32, wl_count, wl_row, wl_cand, attn_out, xatt);
    hipLaunchKernelGGL(out_proj_mfma, dim3(32, 12), dim3(256), 0, stream,
                       xatt, w_out, b_out, xout);
}